// Round 8
// baseline (178.306 us; speedup 1.0000x reference)
//
#include <hip/hip_runtime.h>
#include <math.h>

typedef __attribute__((ext_vector_type(8))) short short8;
typedef __attribute__((ext_vector_type(4))) float f32x4;
typedef __attribute__((ext_vector_type(8))) unsigned short u16x8;

#define TAUF 32.0f

constexpr int B_LO_OFF = 12288;  // lo plane offset within a buffer
constexpr int BUF_SZ   = 24576;  // one B buffer: 192 cols x 32 k x 2 planes
constexpr int CSTR     = 196;    // epilogue C row stride (floats)

// ---------------------------------------------------------------------------
// Kernel 1: PR rows = memory[dm].W as split-bf16 planes [192][768].
// ---------------------------------------------------------------------------
__global__ __launch_bounds__(768) void precompute_pr(
    const float* __restrict__ Wt, const float* __restrict__ Wd,
    const float* __restrict__ mem, unsigned short* __restrict__ PRhi,
    unsigned short* __restrict__ PRlo) {
  int r0 = blockIdx.x * 6, t = threadIdx.x;
  if (r0 >= 180) {
    #pragma unroll
    for (int rr = 0; rr < 6; ++rr) {
      PRhi[(size_t)(r0 + rr) * 768 + t] = 0;
      PRlo[(size_t)(r0 + rr) * 768 + t] = 0;
    }
    return;
  }
  __shared__ float mlds[1536];
  const float* W = (r0 >= 90) ? Wd : Wt;
  int dm0 = (r0 >= 90) ? r0 - 90 : r0;
  for (int i = t; i < 1536; i += 768) mlds[i] = mem[(size_t)dm0 * 256 + i];
  __syncthreads();
  float a[6] = {0.f, 0.f, 0.f, 0.f, 0.f, 0.f};
  #pragma unroll 4
  for (int e = 0; e < 256; ++e) {
    float w = W[(size_t)e * 768 + t];
    #pragma unroll
    for (int rr = 0; rr < 6; ++rr) a[rr] += mlds[rr * 256 + e] * w;
  }
  #pragma unroll
  for (int rr = 0; rr < 6; ++rr) {
    unsigned int bu = __float_as_uint(a[rr]);
    unsigned short hi = (unsigned short)(bu >> 16);
    float hf = __uint_as_float(bu & 0xffff0000u);
    unsigned short lo = (unsigned short)(__float_as_uint(a[rr] - hf) >> 16);
    PRhi[(size_t)(r0 + rr) * 768 + t] = hi;
    PRlo[(size_t)(r0 + rr) * 768 + t] = lo;
  }
}

// ===========================================================================
// Shared device helpers (used identically by real kernel and ablations)
// ===========================================================================
#define DECL_COMMON()                                                        \
  const int t    = threadIdx.x;                                              \
  const int lane = t & 63;                                                   \
  const int wid  = t >> 6;                                                   \
  const int rg   = wid >> 1;                                                 \
  const int cg   = wid & 1;                                                  \
  const int b0   = blockIdx.x * 64;                                          \
  const float* gA0 = feat + (size_t)(b0 + rg * 32 + (lane & 15)) * 768 +     \
                     ((lane >> 4) << 3);                                     \
  const float* gA1 = gA0 + 16 * 768;                                         \
  const int iid  = wid * 6;                                                  \
  const int bc   = lane >> 2;                                                \
  const int bsw  = (lane & 3) ^ ((bc >> 1) & 3);                             \
  const int bsrc = bc * 1536 + bsw * 16;                                     \
  const int bfr  = ((lane & 15) << 6) |                                      \
                   ((((lane >> 4) ^ (((lane & 15) >> 1) & 3)) & 3) << 4);

#define DECL_ISSUEB(smem)                                                    \
  auto issueB = [&](int kt, int bb) {                                        \
    _Pragma("unroll")                                                        \
    for (int u = 0; u < 6; ++u) {                                            \
      int i  = iid + u;                                                      \
      int pl = i >= 12;                                                      \
      int ch = pl ? i - 12 : i;                                              \
      const unsigned short* basep = pl ? PRlo : PRhi;                        \
      const char* gg = (const char*)basep + (size_t)ch * 16 * 1536 +         \
                       kt * 64 + bsrc;                                       \
      char* l = (smem) + bb * BUF_SZ + (pl ? B_LO_OFF : 0) + ch * 1024 +     \
                lane * 16;                                                   \
      __builtin_amdgcn_global_load_lds((const unsigned int*)gg,              \
                                       (unsigned int*)l, 16, 0, 0);          \
    }                                                                        \
  };

#define DECL_APIPE()                                                         \
  float4 Aa0, Aa1, Aa2, Aa3, Ab0, Ab1, Ab2, Ab3;                             \
  auto loadAa = [&](int kt) {                                                \
    Aa0 = *(const float4*)(gA0 + kt * 32);                                   \
    Aa1 = *(const float4*)(gA0 + kt * 32 + 4);                               \
    Aa2 = *(const float4*)(gA1 + kt * 32);                                   \
    Aa3 = *(const float4*)(gA1 + kt * 32 + 4);                               \
  };                                                                         \
  auto loadAb = [&](int kt) {                                                \
    Ab0 = *(const float4*)(gA0 + kt * 32);                                   \
    Ab1 = *(const float4*)(gA0 + kt * 32 + 4);                               \
    Ab2 = *(const float4*)(gA1 + kt * 32);                                   \
    Ab3 = *(const float4*)(gA1 + kt * 32 + 4);                               \
  };

#define DECL_CVT()                                                           \
  short8 ah0, al0, ah1, al1;                                                 \
  float ssq0 = 0.f, ssq1 = 0.f;                                              \
  auto cvtCore = [&](float4 ra0a, float4 ra0b, float4 ra1a, float4 ra1b) {   \
    float x0[8] = {ra0a.x, ra0a.y, ra0a.z, ra0a.w,                           \
                   ra0b.x, ra0b.y, ra0b.z, ra0b.w};                          \
    float x1[8] = {ra1a.x, ra1a.y, ra1a.z, ra1a.w,                           \
                   ra1b.x, ra1b.y, ra1b.z, ra1b.w};                          \
    u16x8 h0, l0, h1, l1;                                                    \
    _Pragma("unroll")                                                        \
    for (int e = 0; e < 8; ++e) {                                            \
      float x = x0[e];                                                       \
      ssq0 += x * x;                                                         \
      unsigned int bu = __float_as_uint(x);                                  \
      h0[e] = (unsigned short)(bu >> 16);                                    \
      l0[e] = (unsigned short)(__float_as_uint(                              \
                  x - __uint_as_float(bu & 0xffff0000u)) >> 16);             \
      float y = x1[e];                                                       \
      ssq1 += y * y;                                                         \
      unsigned int bv = __float_as_uint(y);                                  \
      h1[e] = (unsigned short)(bv >> 16);                                    \
      l1[e] = (unsigned short)(__float_as_uint(                              \
                  y - __uint_as_float(bv & 0xffff0000u)) >> 16);             \
    }                                                                        \
    ah0 = (short8)h0; al0 = (short8)l0; ah1 = (short8)h1; al1 = (short8)l1;  \
  };

#define DECL_ACC()                                                           \
  f32x4 acc0[6], acc1[6];                                                    \
  _Pragma("unroll")                                                          \
  for (int j = 0; j < 6; ++j) {                                              \
    acc0[j] = (f32x4){0.f, 0.f, 0.f, 0.f};                                   \
    acc1[j] = (f32x4){0.f, 0.f, 0.f, 0.f};                                   \
  }

#define DECL_DOMFMA(smem)                                                    \
  auto domfma = [&](int bb) {                                                \
    char* base = (smem) + bb * BUF_SZ;                                       \
    _Pragma("unroll")                                                        \
    for (int j = 0; j < 6; ++j) {                                            \
      int chb = (cg * 6 + j) * 1024;                                         \
      short8 bh = *(const short8*)(base + chb + bfr);                        \
      short8 bl = *(const short8*)(base + B_LO_OFF + chb + bfr);             \
      acc0[j] = __builtin_amdgcn_mfma_f32_16x16x32_bf16(ah0, bh, acc0[j], 0, 0, 0); \
      acc0[j] = __builtin_amdgcn_mfma_f32_16x16x32_bf16(al0, bh, acc0[j], 0, 0, 0); \
      acc0[j] = __builtin_amdgcn_mfma_f32_16x16x32_bf16(ah0, bl, acc0[j], 0, 0, 0); \
      acc1[j] = __builtin_amdgcn_mfma_f32_16x16x32_bf16(ah1, bh, acc1[j], 0, 0, 0); \
      acc1[j] = __builtin_amdgcn_mfma_f32_16x16x32_bf16(al1, bh, acc1[j], 0, 0, 0); \
      acc1[j] = __builtin_amdgcn_mfma_f32_16x16x32_bf16(ah1, bl, acc1[j], 0, 0, 0); \
    }                                                                        \
  };

#define SB() __builtin_amdgcn_sched_barrier(0)
#define BAR() __builtin_amdgcn_s_barrier()

// ---------------------------------------------------------------------------
// Kernel 2 (REAL): triple-buffered B (3 sub-steps deep), A 2 tiles ahead.
// ---------------------------------------------------------------------------
__global__ __launch_bounds__(256, 2) void fused_mfma(
    const float* __restrict__ feat, const unsigned short* __restrict__ PRhi,
    const unsigned short* __restrict__ PRlo, float* __restrict__ out) {
  __shared__ f32x4 smemv[4608];   // 73728 B: 3 B-buffers; C tile overlays
  __shared__ float invn[64];
  __shared__ float sarr[576];
  char* smem = (char*)smemv;

  DECL_COMMON()
  DECL_ISSUEB(smem)
  DECL_APIPE()
  DECL_CVT()
  DECL_ACC()
  DECL_DOMFMA(smem)

  // prologue: B(0,1,2) -> bufs 0,1,2; A(0)->a, A(1)->b
  issueB(0, 0);
  issueB(1, 1);
  issueB(2, 2);
  loadAa(0);
  loadAb(1);
  asm volatile("s_waitcnt vmcnt(20)" ::: "memory");  // B(0) landed
  SB(); BAR();

#define SUBSTEP(kt, SETcvt, BUF, SETload)                                    \
  cvtCore(SETcvt##0, SETcvt##1, SETcvt##2, SETcvt##3);                       \
  domfma(BUF);                                                               \
  SB(); BAR();                                                               \
  issueB((kt) + 3, BUF);                                                     \
  loadA##SETload((kt) + 2);                                                  \
  asm volatile("s_waitcnt vmcnt(16)" ::: "memory");                          \
  SB(); BAR();

  for (int i = 0; i < 3; ++i) {
    int kt0 = 6 * i;
    SUBSTEP(kt0 + 0, Aa, 0, a)
    SUBSTEP(kt0 + 1, Ab, 1, b)
    SUBSTEP(kt0 + 2, Aa, 2, a)
    SUBSTEP(kt0 + 3, Ab, 0, b)
    SUBSTEP(kt0 + 4, Aa, 1, a)
    SUBSTEP(kt0 + 5, Ab, 2, b)
  }
  // tail: kt = 18..23
  SUBSTEP(18, Aa, 0, a)
  SUBSTEP(19, Ab, 1, b)
  SUBSTEP(20, Aa, 2, a)
  // kt=21: no more B to issue; load A(23)
  cvtCore(Ab0, Ab1, Ab2, Ab3);
  domfma(0);
  SB(); BAR();
  loadAb(23);
  asm volatile("s_waitcnt vmcnt(14)" ::: "memory");  // B(22) landed
  SB(); BAR();
  // kt=22
  cvtCore(Aa0, Aa1, Aa2, Aa3);
  domfma(1);
  SB(); BAR();
  asm volatile("s_waitcnt vmcnt(4)" ::: "memory");   // B(23) landed
  SB(); BAR();
  // kt=23
  cvtCore(Ab0, Ab1, Ab2, Ab3);
  domfma(2);
#undef SUBSTEP

  // ---- row L2-norm
  float v0 = ssq0, v1 = ssq1;
  v0 += __shfl_xor(v0, 16, 64); v0 += __shfl_xor(v0, 32, 64);
  v1 += __shfl_xor(v1, 16, 64); v1 += __shfl_xor(v1, 32, 64);
  if (cg == 0 && lane < 16) {
    invn[rg * 32 + lane]      = rsqrtf(v0);
    invn[rg * 32 + 16 + lane] = rsqrtf(v1);
  }
  __syncthreads();

  // ---- write scaled C (q|r) to LDS
  float* Clds = (float*)smem;
  #pragma unroll
  for (int rt = 0; rt < 2; ++rt) {
    int rbase = rg * 32 + rt * 16 + ((lane >> 4) << 2);
    #pragma unroll
    for (int j = 0; j < 6; ++j) {
      int col = cg * 96 + j * 16 + (lane & 15);
      f32x4 v = rt ? acc1[j] : acc0[j];
      #pragma unroll
      for (int jj = 0; jj < 4; ++jj)
        Clds[(rbase + jj) * CSTR + col] = v[jj] * invn[rbase + jj];
    }
  }
  __syncthreads();

  // ---- per (row,d): softmax over m, dot with r
  for (int pid = t; pid < 576; pid += 256) {
    int row = pid / 9, d = pid - row * 9;
    const float* qp = Clds + row * CSTR + d * 10;
    const float* rp = qp + 90;
    float mx = qp[0];
    #pragma unroll
    for (int m = 1; m < 10; ++m) mx = fmaxf(mx, qp[m]);
    float s = 0.f, val = 0.f;
    #pragma unroll
    for (int m = 0; m < 10; ++m) {
      float e = __expf(TAUF * (qp[m] - mx));
      s += e;
      val += e * rp[m];
    }
    sarr[pid] = val / s;
  }
  __syncthreads();

  // ---- per row: softmax over d, write out
  if (t < 64) {
    float v[9];
    #pragma unroll
    for (int d = 0; d < 9; ++d) v[d] = sarr[t * 9 + d];
    float mx = v[0];
    #pragma unroll
    for (int d = 1; d < 9; ++d) mx = fmaxf(mx, v[d]);
    float s = 0.f;
    float e[9];
    #pragma unroll
    for (int d = 0; d < 9; ++d) {
      e[d] = __expf(TAUF * (v[d] - mx));
      s += e[d];
    }
    float is = 1.f / s;
    #pragma unroll
    for (int d = 0; d < 9; ++d)
      out[(size_t)(b0 + t) * 9 + d] = e[d] * is;
  }
}

// ---------------------------------------------------------------------------
// ABLATION 1: loads + DMA + waits + barriers only (no cvt/MFMA/ds_read).
// ---------------------------------------------------------------------------
__global__ __launch_bounds__(256, 2) void abl_load_only(
    const float* __restrict__ feat, const unsigned short* __restrict__ PRhi,
    const unsigned short* __restrict__ PRlo) {
  __shared__ f32x4 smemv[3072];   // 49152 B: 2 buffers
  char* smem = (char*)smemv;
  DECL_COMMON()
  DECL_ISSUEB(smem)
  DECL_APIPE()
  (void)bfr; (void)gA1;

#define KEEPA(S)                                                             \
  asm volatile("" :: "v"((S##0).x), "v"((S##1).x), "v"((S##2).x),            \
               "v"((S##3).x));

  issueB(0, 0);
  issueB(1, 1);
  loadAa(0);
  loadAb(1);
  asm volatile("s_waitcnt vmcnt(14)" ::: "memory");
  SB(); BAR();
  for (int kp = 0; kp < 11; ++kp) {
    int kt = 2 * kp;
    KEEPA(Aa)
    SB(); BAR();
    issueB(kt + 2, 0);
    loadAa(kt + 2);
    asm volatile("s_waitcnt vmcnt(14)" ::: "memory");
    SB(); BAR();
    KEEPA(Ab)
    SB(); BAR();
    issueB(kt + 3, 1);
    loadAb(kt + 3);
    asm volatile("s_waitcnt vmcnt(14)" ::: "memory");
    SB(); BAR();
  }
  KEEPA(Aa)
  SB(); BAR();
  asm volatile("s_waitcnt vmcnt(0)" ::: "memory");
  SB(); BAR();
  KEEPA(Ab)
#undef KEEPA
}

// ---------------------------------------------------------------------------
// ABLATION 2: cvt + ds_read + MFMA + barriers only (no global loads in loop).
// ---------------------------------------------------------------------------
__global__ __launch_bounds__(256, 2) void abl_mfma_only(
    const float* __restrict__ feat, const unsigned short* __restrict__ PRhi,
    const unsigned short* __restrict__ PRlo) {
  __shared__ f32x4 smemv[3072];
  char* smem = (char*)smemv;
  DECL_COMMON()
  DECL_ISSUEB(smem)
  DECL_APIPE()
  DECL_CVT()
  DECL_ACC()
  DECL_DOMFMA(smem)

  issueB(0, 0);
  issueB(1, 1);
  loadAa(0);
  loadAb(1);
  asm volatile("s_waitcnt vmcnt(0)" ::: "memory");
  SB(); BAR();
  for (int kp = 0; kp < 11; ++kp) {
    cvtCore(Aa0, Aa1, Aa2, Aa3);
    domfma(0);
    SB(); BAR();
    SB(); BAR();
    cvtCore(Ab0, Ab1, Ab2, Ab3);
    domfma(1);
    SB(); BAR();
    SB(); BAR();
  }
  cvtCore(Aa0, Aa1, Aa2, Aa3);
  domfma(0);
  SB(); BAR();
  cvtCore(Ab0, Ab1, Ab2, Ab3);
  domfma(1);

  float keep = ssq0 + ssq1;
  #pragma unroll
  for (int j = 0; j < 6; ++j) keep += acc0[j][0] + acc1[j][0];
  asm volatile("" :: "v"(keep));
}

// ---------------------------------------------------------------------------
// ABLATION 3: full R5 loop with NO barriers (racy values; timing only).
// ---------------------------------------------------------------------------
__global__ __launch_bounds__(256, 2) void abl_no_barrier(
    const float* __restrict__ feat, const unsigned short* __restrict__ PRhi,
    const unsigned short* __restrict__ PRlo) {
  __shared__ f32x4 smemv[3072];
  char* smem = (char*)smemv;
  DECL_COMMON()
  DECL_ISSUEB(smem)
  DECL_APIPE()
  DECL_CVT()
  DECL_ACC()
  DECL_DOMFMA(smem)

  issueB(0, 0);
  issueB(1, 1);
  loadAa(0);
  loadAb(1);
  asm volatile("s_waitcnt vmcnt(14)" ::: "memory");
  SB();
  for (int kp = 0; kp < 11; ++kp) {
    int kt = 2 * kp;
    cvtCore(Aa0, Aa1, Aa2, Aa3);
    domfma(0);
    issueB(kt + 2, 0);
    loadAa(kt + 2);
    asm volatile("s_waitcnt vmcnt(14)" ::: "memory");
    SB();
    cvtCore(Ab0, Ab1, Ab2, Ab3);
    domfma(1);
    issueB(kt + 3, 1);
    loadAb(kt + 3);
    asm volatile("s_waitcnt vmcnt(14)" ::: "memory");
    SB();
  }
  cvtCore(Aa0, Aa1, Aa2, Aa3);
  domfma(0);
  asm volatile("s_waitcnt vmcnt(0)" ::: "memory");
  SB();
  cvtCore(Ab0, Ab1, Ab2, Ab3);
  domfma(1);

  float keep = ssq0 + ssq1;
  #pragma unroll
  for (int j = 0; j < 6; ++j) keep += acc0[j][0] + acc1[j][0];
  asm volatile("" :: "v"(keep));
}

extern "C" void kernel_launch(void* const* d_in, const int* in_sizes, int n_in,
                              void* d_out, int out_size, void* d_ws, size_t ws_size,
                              hipStream_t stream) {
  const float* feat = (const float*)d_in[0];
  // d_in[1] = category (unused by forward math)
  const float* Wt  = (const float*)d_in[2];
  const float* Wd  = (const float*)d_in[3];
  const float* mem = (const float*)d_in[4];
  float* outp = (float*)d_out;

  unsigned short* PRhi = (unsigned short*)d_ws;   // [192][768] bf16
  unsigned short* PRlo = PRhi + 192 * 768;        // [192][768] bf16

  precompute_pr<<<32, 768, 0, stream>>>(Wt, Wd, mem, PRhi, PRlo);
  const int B = in_sizes[1];   // 32768
  const int nblk = B / 64;     // 512
  fused_mfma<<<nblk, 256, 0, stream>>>(feat, PRhi, PRlo, outp);
  // ---- ablation probes (timing only; write nothing) ----
  abl_load_only<<<nblk, 256, 0, stream>>>(feat, PRhi, PRlo);
  abl_mfma_only<<<nblk, 256, 0, stream>>>(feat, PRhi, PRlo);
  abl_no_barrier<<<nblk, 256, 0, stream>>>(feat, PRhi, PRlo);
}